// Round 10
// baseline (179.617 us; speedup 1.0000x reference)
//
#include <hip/hip_runtime.h>
#include <hip/hip_bf16.h>
#include <stdint.h>

typedef __attribute__((ext_vector_type(4))) float f32x4;
typedef __attribute__((ext_vector_type(8))) __bf16 bf16x8;
typedef unsigned short u16;
typedef unsigned int u32;
typedef unsigned long long u64;

#define NH 16
#define DKK 64

// round-to-nearest-even fp32 -> bf16
__device__ __forceinline__ u16 f2bf(float f) {
    u32 u = __builtin_bit_cast(u32, f);
    u32 r = (u + 0x7fffu + ((u >> 16) & 1u)) >> 16;
    return (u16)r;
}

__device__ __forceinline__ u16 cvt_bf(float f) {
    __hip_bfloat16 h = __float2bfloat16(f);
    return *reinterpret_cast<u16*>(&h);
}

__device__ __forceinline__ void gload16(const void* g, void* l) {
    __builtin_amdgcn_global_load_lds((const __attribute__((address_space(1))) void*)g,
                                     (__attribute__((address_space(3))) void*)l, 16, 0, 0);
}

// ---------------- convert X fp32 -> bf16 (row-major [8192][1024]) ----------------
__global__ __launch_bounds__(256) void k_convert_x(const float* __restrict__ x,
                                                   u16* __restrict__ xb) {
    int i = blockIdx.x * 256 + threadIdx.x;          // one 8-elem chunk each
    const float4* p = (const float4*)x + (size_t)i * 2;
    float4 a = p[0], b = p[1];
    union { u16 h[8]; uint4 q; } o;
    o.h[0] = f2bf(a.x); o.h[1] = f2bf(a.y); o.h[2] = f2bf(a.z); o.h[3] = f2bf(a.w);
    o.h[4] = f2bf(b.x); o.h[5] = f2bf(b.y); o.h[6] = f2bf(b.z); o.h[7] = f2bf(b.w);
    ((uint4*)xb)[i] = o.q;
}

// ---------------- transpose-convert W[k][n] fp32 -> Wt[w][n][k] bf16 ----------------
__global__ __launch_bounds__(256) void k_convert_w(const float* __restrict__ wq,
                                                   const float* __restrict__ wk,
                                                   const float* __restrict__ wv,
                                                   const float* __restrict__ wo,
                                                   u16* __restrict__ wt) {
    int z = blockIdx.z;
    const float* w = (z == 0) ? wq : (z == 1) ? wk : (z == 2) ? wv : wo;
    __shared__ float t[32][33];
    int tx = threadIdx.x & 31, ty = threadIdx.x >> 5;
    int n0 = blockIdx.x * 32, k0 = blockIdx.y * 32;
    for (int rr = 0; rr < 4; ++rr)
        t[ty + rr * 8][tx] = w[(size_t)(k0 + ty + rr * 8) * 1024 + n0 + tx];
    __syncthreads();
    for (int rr = 0; rr < 4; ++rr) {
        int n = n0 + ty + rr * 8;
        wt[((size_t)z * 1024 + n) * 1024 + k0 + tx] = f2bf(t[tx][ty + rr * 8]);
    }
}

// ------- pack mask int32 [8][1024 row][1024 col] -> bitmask u64 [8][16 t][1024 row] -
__global__ __launch_bounds__(256) void k_maskpack(const int* __restrict__ mask,
                                                  u64* __restrict__ mb) {
    int wid = (blockIdx.x * 256 + threadIdx.x) >> 6;
    int lane = threadIdx.x & 63;
    for (int c = wid; c < 8 * 1024 * 16; c += 8192) {
        int m = mask[(size_t)c * 64 + lane];
        u64 bits = __ballot(m != 0);
        // c = (b*1024 + row)*16 + t  ->  out = (b*16 + t)*1024 + row
        if (lane == 0)
            mb[(c & 0xFFFFC000u) | ((c & 15) << 10) | ((c >> 4) & 1023)] = bits;
    }
}

// ---------------- GEMM: Y[M][N] = A[M][1024] @ Bt[N][1024]^T (+bias, epilogue) ------
// Round-9 proven (66.8 µs): 16KB LDS pair, 2 barriers/K-step, chunk-XOR swizzle
// (0 bank conflicts), round-5 epilogue (VGPR 80). UNCHANGED this round.
template <int MODE>
__global__ __launch_bounds__(256) void k_gemm(const u16* __restrict__ A,
                                              const u16* __restrict__ Bt,
                                              const float* __restrict__ b0,
                                              const float* __restrict__ b1,
                                              const float* __restrict__ b2,
                                              u16* __restrict__ q_out,
                                              u16* __restrict__ k_out,
                                              u16* __restrict__ v_out,
                                              float* __restrict__ out) {
    __shared__ u16 As[128 * 32];
    __shared__ u16 Bs[128 * 32];
    int tid = threadIdx.x;
    int wv = tid >> 6, lane = tid & 63;
    int r = lane & 15, g = lane >> 4;
    int wr = wv >> 1, wc = wv & 1;
    int m0 = blockIdx.x * 128, n0 = blockIdx.y * 128;
    f32x4 acc[4][4] = {};
    for (int kt = 0; kt < 1024; kt += 32) {
        __syncthreads();
        for (int i = 0; i < 2; ++i) {
            int e = i * 256 + tid;
            int row = e >> 2;
            int cs = ((e & 3) ^ ((row >> 1) & 3)) * 8;   // pre-swizzled source chunk
            const u16* ga = A + (size_t)(m0 + row) * 1024 + kt + cs;
            const u16* gb = Bt + (size_t)(n0 + row) * 1024 + kt + cs;
            gload16(ga, As + (size_t)(i * 256 + wv * 64) * 8);
            gload16(gb, Bs + (size_t)(i * 256 + wv * 64) * 8);
        }
        __syncthreads();
        bf16x8 aF[4], bF[4];
#pragma unroll
        for (int m = 0; m < 4; ++m) {
            int ro = wr * 64 + m * 16 + r;
            aF[m] = *(const bf16x8*)&As[ro * 32 + ((g ^ ((ro >> 1) & 3)) << 3)];
        }
#pragma unroll
        for (int n = 0; n < 4; ++n) {
            int ro = wc * 64 + n * 16 + r;
            bF[n] = *(const bf16x8*)&Bs[ro * 32 + ((g ^ ((ro >> 1) & 3)) << 3)];
        }
#pragma unroll
        for (int m = 0; m < 4; ++m)
#pragma unroll
            for (int n = 0; n < 4; ++n)
                acc[m][n] = __builtin_amdgcn_mfma_f32_16x16x32_bf16(aF[m], bF[n], acc[m][n], 0, 0, 0);
    }
    // epilogue: lane (g,r) holds D[4g+i][r] of each 16x16 frag (round-5 form)
    for (int m = 0; m < 4; ++m) {
        int rowb = m0 + wr * 64 + m * 16 + 4 * g;
        for (int n = 0; n < 4; ++n) {
            int col = n0 + wc * 64 + n * 16 + r;
            if (MODE == 0) {
                int w = col >> 10, cn = col & 1023;
                const float* bp = (w == 0) ? b0 : (w == 1) ? b1 : b2;
                u16* dst = (w == 0) ? q_out : (w == 1) ? k_out : v_out;
                float sc = (w == 0) ? 0.125f : 1.0f;
                int h = cn >> 6, d = cn & 63;
                float bias = bp[cn];
                for (int i = 0; i < 4; ++i) {
                    int row = rowb + i;
                    int b = row >> 10, s = row & 1023;
                    float v = (acc[m][n][i] + bias) * sc;
                    dst[((size_t)(b * NH + h) * 1024 + s) * 64 + d] = f2bf(v);
                }
            } else {
                float bias = b0[col];
                for (int i = 0; i < 4; ++i) {
                    int row = rowb + i;
                    out[(size_t)row * 1024 + col] = acc[m][n][i] + bias;
                }
            }
        }
    }
}

// ---------------- transpose V: Vb[bh][s][64] -> Vt[bh][d][1024] ----------------
__global__ __launch_bounds__(256) void k_transpose_v(const u16* __restrict__ vb,
                                                     u16* __restrict__ vt) {
    __shared__ u16 t[64][72];
    int bh = blockIdx.y, s0 = blockIdx.x * 64;
    int tid = threadIdx.x;
    for (int i = 0; i < 2; ++i) {
        int e = i * 256 + tid;
        int row = e >> 3, ch = (e & 7) * 8;
        uint4 v = *(const uint4*)(vb + ((size_t)bh * 1024 + s0 + row) * 64 + ch);
        *(uint4*)&t[row][ch] = v;
    }
    __syncthreads();
    for (int i = 0; i < 2; ++i) {
        int e = i * 256 + tid;
        int d = e >> 3, ch = (e & 7) * 8;
        union { u16 h[8]; uint4 q; } o;
        for (int j = 0; j < 8; ++j) o.h[j] = t[ch + j][d];
        *(uint4*)(vt + ((size_t)bh * 64 + d) * 1024 + s0 + ch) = o.q;
    }
}

// ---------------- fused masked attention v6 ----------------
// v5 compute structure + T4 counted-vmcnt ring:
//  - 3-slot K/V LDS ring (48 KB), depth-2 prefetch: stage(t+2) at iter start;
//    end-of-iter s_waitcnt vmcnt(4) (drains ONLY tile t+1; t+2's 4 loads stay
//    in flight across the barrier) + raw s_barrier (no compiler vmcnt(0) drain).
//    Invariant: tile t landed at iter-t start; slot (t+2)%3's last reader
//    passed the iter-(t-1) barrier.
//  - mask bits fully preloaded to registers (8 u64/lane: lane (r,g) holds
//    tiles g*4+j); per tile one 64-wide shfl broadcast -> ZERO in-loop vmem,
//    making the manual vmcnt counts exact. Static mbq indexing via tt/j split.
//  - setprio(1) around pure-MFMA clusters (T5, m191 attn +4-7%).
__global__ __launch_bounds__(256, 3) void k_attn(const u16* __restrict__ qb,
                                                 const u16* __restrict__ kb,
                                                 const u16* __restrict__ vt,
                                                 const u64* __restrict__ mbits,
                                                 u16* __restrict__ ctx) {
    __shared__ u16 Kd[3][64 * 64];
    __shared__ u16 Vd[3][64 * 64];
    int tid = threadIdx.x, wv = tid >> 6, lane = tid & 63;
    int r = lane & 15, g = lane >> 4;
    int q0 = blockIdx.x * 128, bh = blockIdx.y;
    int b = bh >> 4, h = bh & 15;

    // Q fragments: 2 q-groups of 16 rows (B-operand: lane holds Q[q=r][g*8..])
    bf16x8 aq[2][2];
#pragma unroll
    for (int qg = 0; qg < 2; ++qg) {
        const u16* qp = qb + ((size_t)bh * 1024 + q0 + wv * 32 + qg * 16 + r) * 64 + g * 8;
        aq[qg][0] = *(const bf16x8*)qp;
        aq[qg][1] = *(const bf16x8*)(qp + 32);
    }

    // mask preload: lane (r,g) holds u64 for tiles g*4+j, rows (qg*16+r) of this wave
    const u64* mbase = mbits + (size_t)b * 16384 + q0 + wv * 32;
    u64 mbq0[4], mbq1[4];
#pragma unroll
    for (int j = 0; j < 4; ++j) {
        mbq0[j] = mbase[(size_t)(g * 4 + j) * 1024 + r];
        mbq1[j] = mbase[(size_t)(g * 4 + j) * 1024 + 16 + r];
    }

    f32x4 of[2][4] = {};
    f32x4 zacc[2] = {};
    const bf16x8 vone = {(__bf16)1.f, (__bf16)1.f, (__bf16)1.f, (__bf16)1.f,
                         (__bf16)1.f, (__bf16)1.f, (__bf16)1.f, (__bf16)1.f};

#define ATTN_STAGE(slot, ktn)                                                          \
    {                                                                                  \
        for (int i2 = 0; i2 < 2; ++i2) {                                               \
            int e = i2 * 256 + tid;                                                    \
            int s = e >> 3, c = e & 7;                                                 \
            int cs = (c ^ (s & 7)) * 8;                                                \
            int kr = (s & 0x20) | ((s & 0x0C) << 1) | ((s & 0x10) >> 2) | (s & 3);     \
            gload16(kb + ((size_t)bh * 1024 + (ktn) + kr) * 64 + cs,                   \
                    Kd[slot] + (size_t)e * 8);                                         \
            gload16(vt + ((size_t)bh * 64 + s) * 1024 + (ktn) + cs,                    \
                    Vd[slot] + (size_t)e * 8);                                         \
        }                                                                              \
    }

    // prologue: stage tiles 0,1; wait tile 0 only (4 of 8 loads may remain in flight)
    ATTN_STAGE(0, 0);
    ATTN_STAGE(1, 64);
    asm volatile("s_waitcnt vmcnt(4)" ::: "memory");
    __builtin_amdgcn_s_barrier();

    int cur = 0, s2 = 2;
    for (int tt = 0; tt < 4; ++tt) {
#pragma unroll
        for (int j = 0; j < 4; ++j) {
            int t = tt * 4 + j;
            if (t < 14) ATTN_STAGE(s2, (t + 2) * 64);
            const u16* K = Kd[cur];
            const u16* V = Vd[cur];

            // broadcast this tile's mask bits (no vmem)
            int srcl = (tt << 4) + r;
            u64 mb64[2];
            mb64[0] = __shfl(mbq0[j], srcl, 64);
            mb64[1] = __shfl(mbq1[j], srcl, 64);

            // K A-fragments (shared by both q-groups)
            bf16x8 bk0[4], bk1[4];
#pragma unroll
            for (int nf = 0; nf < 4; ++nf) {
                int rowk = (nf * 16 + r) * 64;
                bk0[nf] = *(const bf16x8*)&K[rowk + ((g ^ (r & 7)) << 3)];
                bk1[nf] = *(const bf16x8*)&K[rowk + (((g + 4) ^ (r & 7)) << 3)];
            }

            bf16x8 pfr[2][2];
#pragma unroll
            for (int qg = 0; qg < 2; ++qg) {
                // S^T: lane (r,g) gets S[q=r][kappa(16nf+4g+i)]
                f32x4 sf[4];
                __builtin_amdgcn_s_setprio(1);
#pragma unroll
                for (int nf = 0; nf < 4; ++nf) {
                    f32x4 z = {0.f, 0.f, 0.f, 0.f};
                    z = __builtin_amdgcn_mfma_f32_16x16x32_bf16(bk0[nf], aq[qg][0], z, 0, 0, 0);
                    sf[nf] = __builtin_amdgcn_mfma_f32_16x16x32_bf16(bk1[nf], aq[qg][1], z, 0, 0, 0);
                }
                __builtin_amdgcn_s_setprio(0);
                // masked exp -> packed bf16 pairs == PV B-fragments
                u64 m64 = mb64[qg] >> (g * 8);
                u32 mlo = (u32)m64, mhi = (u32)(m64 >> 32);
                u32 pw[8];
#pragma unroll
                for (int nf = 0; nf < 4; ++nf) {
                    u32 nib = ((nf & 2) ? mhi : mlo) >> ((nf & 1) * 4);
                    u32 pm0 = ((nib & 1) ? 0xFFFFu : 0u) | ((nib & 2) ? 0xFFFF0000u : 0u);
                    u32 pm1 = ((nib & 4) ? 0xFFFFu : 0u) | ((nib & 8) ? 0xFFFF0000u : 0u);
                    float e0 = __expf(sf[nf][0]), e1 = __expf(sf[nf][1]);
                    float e2 = __expf(sf[nf][2]), e3 = __expf(sf[nf][3]);
                    pw[2 * nf]     = (((u32)cvt_bf(e0)) | ((u32)cvt_bf(e1) << 16)) & pm0;
                    pw[2 * nf + 1] = (((u32)cvt_bf(e2)) | ((u32)cvt_bf(e3) << 16)) & pm1;
                }
                union { u32 w[4]; bf16x8 v; } f0, f1;
                f0.w[0] = pw[0]; f0.w[1] = pw[1]; f0.w[2] = pw[2]; f0.w[3] = pw[3];
                f1.w[0] = pw[4]; f1.w[1] = pw[5]; f1.w[2] = pw[6]; f1.w[3] = pw[7];
                pfr[qg][0] = f0.v;
                pfr[qg][1] = f1.v;
                // Zm = row-sum via ones-MFMA (all output rows identical)
                __builtin_amdgcn_s_setprio(1);
                zacc[qg] = __builtin_amdgcn_mfma_f32_16x16x32_bf16(vone, pfr[qg][0], zacc[qg], 0, 0, 0);
                zacc[qg] = __builtin_amdgcn_mfma_f32_16x16x32_bf16(vone, pfr[qg][1], zacc[qg], 0, 0, 0);
                __builtin_amdgcn_s_setprio(0);
            }
            // PV: A = V (d-rows), B = P-frags; out = ctx^T fragments
            __builtin_amdgcn_s_setprio(1);
#pragma unroll
            for (int ks = 0; ks < 2; ++ks) {
#pragma unroll
                for (int nf = 0; nf < 4; ++nf) {
                    bf16x8 av = *(const bf16x8*)&V[(nf * 16 + r) * 64 + (((ks * 4 + g) ^ (r & 7)) << 3)];
                    of[0][nf] = __builtin_amdgcn_mfma_f32_16x16x32_bf16(av, pfr[0][ks], of[0][nf], 0, 0, 0);
                    of[1][nf] = __builtin_amdgcn_mfma_f32_16x16x32_bf16(av, pfr[1][ks], of[1][nf], 0, 0, 0);
                }
            }
            __builtin_amdgcn_s_setprio(0);

            // counted wait: drain tile t+1 ONLY (t+2 stays in flight across barrier)
            if (t < 14) {
                asm volatile("s_waitcnt vmcnt(4)" ::: "memory");
                __builtin_amdgcn_s_barrier();
            } else if (t == 14) {
                asm volatile("s_waitcnt vmcnt(0)" ::: "memory");
                __builtin_amdgcn_s_barrier();
            }
            cur = (cur == 2) ? 0 : cur + 1;
            s2 = (s2 == 2) ? 0 : s2 + 1;
        }
    }

    // epilogue: lane (r,g) owns q-row r of group qg; d = 16nf + 4g + i
#pragma unroll
    for (int qg = 0; qg < 2; ++qg) {
        float inv = 1.0f / zacc[qg][0];
        int qrow = q0 + wv * 32 + qg * 16 + r;
        u16* crow = ctx + ((size_t)(b * 1024 + qrow)) * 1024 + h * 64;
#pragma unroll
        for (int nf = 0; nf < 4; ++nf) {
            u32 w0 = ((u32)cvt_bf(of[qg][nf][0] * inv)) | ((u32)cvt_bf(of[qg][nf][1] * inv) << 16);
            u32 w1 = ((u32)cvt_bf(of[qg][nf][2] * inv)) | ((u32)cvt_bf(of[qg][nf][3] * inv) << 16);
            *(u32*)(crow + nf * 16 + g * 4) = w0;
            *(u32*)(crow + nf * 16 + g * 4 + 2) = w1;
        }
    }
#undef ATTN_STAGE
}

extern "C" void kernel_launch(void* const* d_in, const int* in_sizes, int n_in,
                              void* d_out, int out_size, void* d_ws, size_t ws_size,
                              hipStream_t stream) {
    const float* Q_in = (const float*)d_in[0];
    const int*   mask = (const int*)d_in[1];
    const float* Wq = (const float*)d_in[2];
    const float* bq = (const float*)d_in[3];
    const float* Wk = (const float*)d_in[4];
    const float* bk = (const float*)d_in[5];
    const float* Wv = (const float*)d_in[6];
    const float* bv = (const float*)d_in[7];
    const float* Wo = (const float*)d_in[8];
    const float* bo = (const float*)d_in[9];

    char* ws = (char*)d_ws;
    u16* Xb = (u16*)(ws);                      // 16.78 MB  [8192][1024] bf16
    u16* Wt = (u16*)(ws + 16777216);           //  8.39 MB  [4][1024 n][1024 k] bf16
    u16* Qb = (u16*)(ws + 25165824);           // 16.78 MB  [B,H,S,dk] bf16 (x 0.125)
    u16* Kb = (u16*)(ws + 41943040);           // 16.78 MB  [B,H,S,dk]
    u16* Vb = (u16*)(ws + 58720256);           // 16.78 MB  [B,H,S,dk]
    u16* Vt = (u16*)(ws + 75497472);           // 16.78 MB  [B,H,dk,S]
    u64* Mb = (u64*)(ws + 92274688);           //  1.05 MB  [8][16 t][1024 row] u64
    u16* Ctx = Vb;                             // reuse Vb after transpose

    k_convert_x<<<4096, 256, 0, stream>>>(Q_in, Xb);
    k_convert_w<<<dim3(32, 32, 4), 256, 0, stream>>>(Wq, Wk, Wv, Wo, Wt);
    k_maskpack<<<2048, 256, 0, stream>>>(mask, Mb);
    k_gemm<0><<<dim3(64, 24), 256, 0, stream>>>(Xb, Wt, bq, bk, bv, Qb, Kb, Vb, nullptr);
    k_transpose_v<<<dim3(16, 128), 256, 0, stream>>>(Vb, Vt);
    k_attn<<<dim3(8, 128), 256, 0, stream>>>(Qb, Kb, Vt, Mb, Ctx);
    k_gemm<1><<<dim3(64, 8), 256, 0, stream>>>(Ctx, Wt + (size_t)3 * 1024 * 1024,
                                               bo, nullptr, nullptr,
                                               nullptr, nullptr, nullptr, (float*)d_out);
}

// Round 13
// 173.215 us; speedup vs baseline: 1.0370x; 1.0370x over previous
//
#include <hip/hip_runtime.h>
#include <hip/hip_bf16.h>
#include <stdint.h>

typedef __attribute__((ext_vector_type(4))) float f32x4;
typedef __attribute__((ext_vector_type(8))) __bf16 bf16x8;
typedef unsigned short u16;
typedef unsigned int u32;
typedef unsigned long long u64;

#define NH 16
#define DKK 64
// Q projection scale: (1/sqrt(64)) * log2(e)  -> attn uses exp2 directly
#define QSCALE 0.18033688011112042f

// round-to-nearest-even fp32 -> bf16
__device__ __forceinline__ u16 f2bf(float f) {
    u32 u = __builtin_bit_cast(u32, f);
    u32 r = (u + 0x7fffu + ((u >> 16) & 1u)) >> 16;
    return (u16)r;
}

__device__ __forceinline__ u16 cvt_bf(float f) {
    __hip_bfloat16 h = __float2bfloat16(f);
    return *reinterpret_cast<u16*>(&h);
}

// bare v_exp_f32 (2^x); avoids glibc __exp2f macro clash
__device__ __forceinline__ float exp2_fast(float x) {
    return __builtin_amdgcn_exp2f(x);
}

__device__ __forceinline__ void gload16(const void* g, void* l) {
    __builtin_amdgcn_global_load_lds((const __attribute__((address_space(1))) void*)g,
                                     (__attribute__((address_space(3))) void*)l, 16, 0, 0);
}

// ---------------- fused prep: convert X | transpose-convert W | pack mask ----------
// blocks [0,4096): X fp32->bf16 ; [4096,8192): W transpose ; [8192,10240): maskpack
__global__ __launch_bounds__(256) void k_prep(const float* __restrict__ x,
                                              u16* __restrict__ xb,
                                              const float* __restrict__ wq,
                                              const float* __restrict__ wk,
                                              const float* __restrict__ wv,
                                              const float* __restrict__ wo,
                                              u16* __restrict__ wt,
                                              const int* __restrict__ mask,
                                              u64* __restrict__ mb) {
    int bx = blockIdx.x;
    if (bx < 4096) {
        int i = bx * 256 + threadIdx.x;              // one 8-elem chunk each
        const float4* p = (const float4*)x + (size_t)i * 2;
        float4 a = p[0], b = p[1];
        union { u16 h[8]; uint4 q; } o;
        o.h[0] = f2bf(a.x); o.h[1] = f2bf(a.y); o.h[2] = f2bf(a.z); o.h[3] = f2bf(a.w);
        o.h[4] = f2bf(b.x); o.h[5] = f2bf(b.y); o.h[6] = f2bf(b.z); o.h[7] = f2bf(b.w);
        ((uint4*)xb)[i] = o.q;
    } else if (bx < 8192) {
        int idx = bx - 4096;
        int z = idx >> 10;
        const float* w = (z == 0) ? wq : (z == 1) ? wk : (z == 2) ? wv : wo;
        __shared__ float t[32][33];
        int tx = threadIdx.x & 31, ty = threadIdx.x >> 5;
        int n0 = (idx & 31) * 32, k0 = ((idx >> 5) & 31) * 32;
        for (int rr = 0; rr < 4; ++rr)
            t[ty + rr * 8][tx] = w[(size_t)(k0 + ty + rr * 8) * 1024 + n0 + tx];
        __syncthreads();
        for (int rr = 0; rr < 4; ++rr) {
            int n = n0 + ty + rr * 8;
            wt[((size_t)z * 1024 + n) * 1024 + k0 + tx] = f2bf(t[tx][ty + rr * 8]);
        }
    } else {
        int wid = ((bx - 8192) * 256 + threadIdx.x) >> 6;
        int lane = threadIdx.x & 63;
        for (int c = wid; c < 8 * 1024 * 16; c += 8192) {
            int m = mask[(size_t)c * 64 + lane];
            u64 bits = __ballot(m != 0);
            // c = (b*1024 + row)*16 + t  ->  out = (b*16 + t)*1024 + row
            if (lane == 0)
                mb[(c & 0xFFFFC000u) | ((c & 15) << 10) | ((c >> 4) & 1023)] = bits;
        }
    }
}

// ---------------- GEMM: Y[M][N] = A[M][1024] @ Bt[N][1024]^T (+bias, epilogue) ------
// Round-9 proven (66.8 µs): 16KB LDS pair, 2 barriers/K-step, chunk-XOR swizzle
// (0 bank conflicts), round-5 epilogue (VGPR 80). Q scale = QSCALE (folds log2e).
template <int MODE>
__global__ __launch_bounds__(256) void k_gemm(const u16* __restrict__ A,
                                              const u16* __restrict__ Bt,
                                              const float* __restrict__ b0,
                                              const float* __restrict__ b1,
                                              const float* __restrict__ b2,
                                              u16* __restrict__ q_out,
                                              u16* __restrict__ k_out,
                                              u16* __restrict__ v_out,
                                              float* __restrict__ out) {
    __shared__ u16 As[128 * 32];
    __shared__ u16 Bs[128 * 32];
    int tid = threadIdx.x;
    int wv = tid >> 6, lane = tid & 63;
    int r = lane & 15, g = lane >> 4;
    int wr = wv >> 1, wc = wv & 1;
    int m0 = blockIdx.x * 128, n0 = blockIdx.y * 128;
    f32x4 acc[4][4] = {};
    for (int kt = 0; kt < 1024; kt += 32) {
        __syncthreads();
        for (int i = 0; i < 2; ++i) {
            int e = i * 256 + tid;
            int row = e >> 2;
            int cs = ((e & 3) ^ ((row >> 1) & 3)) * 8;   // pre-swizzled source chunk
            const u16* ga = A + (size_t)(m0 + row) * 1024 + kt + cs;
            const u16* gb = Bt + (size_t)(n0 + row) * 1024 + kt + cs;
            gload16(ga, As + (size_t)(i * 256 + wv * 64) * 8);
            gload16(gb, Bs + (size_t)(i * 256 + wv * 64) * 8);
        }
        __syncthreads();
        bf16x8 aF[4], bF[4];
#pragma unroll
        for (int m = 0; m < 4; ++m) {
            int ro = wr * 64 + m * 16 + r;
            aF[m] = *(const bf16x8*)&As[ro * 32 + ((g ^ ((ro >> 1) & 3)) << 3)];
        }
#pragma unroll
        for (int n = 0; n < 4; ++n) {
            int ro = wc * 64 + n * 16 + r;
            bF[n] = *(const bf16x8*)&Bs[ro * 32 + ((g ^ ((ro >> 1) & 3)) << 3)];
        }
#pragma unroll
        for (int m = 0; m < 4; ++m)
#pragma unroll
            for (int n = 0; n < 4; ++n)
                acc[m][n] = __builtin_amdgcn_mfma_f32_16x16x32_bf16(aF[m], bF[n], acc[m][n], 0, 0, 0);
    }
    // epilogue: lane (g,r) holds D[4g+i][r] of each 16x16 frag (round-5 form)
    for (int m = 0; m < 4; ++m) {
        int rowb = m0 + wr * 64 + m * 16 + 4 * g;
        for (int n = 0; n < 4; ++n) {
            int col = n0 + wc * 64 + n * 16 + r;
            if (MODE == 0) {
                int w = col >> 10, cn = col & 1023;
                const float* bp = (w == 0) ? b0 : (w == 1) ? b1 : b2;
                u16* dst = (w == 0) ? q_out : (w == 1) ? k_out : v_out;
                float sc = (w == 0) ? QSCALE : 1.0f;
                int h = cn >> 6, d = cn & 63;
                float bias = bp[cn];
                for (int i = 0; i < 4; ++i) {
                    int row = rowb + i;
                    int b = row >> 10, s = row & 1023;
                    float v = (acc[m][n][i] + bias) * sc;
                    dst[((size_t)(b * NH + h) * 1024 + s) * 64 + d] = f2bf(v);
                }
            } else {
                float bias = b0[col];
                for (int i = 0; i < 4; ++i) {
                    int row = rowb + i;
                    out[(size_t)row * 1024 + col] = acc[m][n][i] + bias;
                }
            }
        }
    }
}

// ---------------- transpose V: Vb[bh][s][64] -> Vt[bh][d][1024] ----------------
__global__ __launch_bounds__(256) void k_transpose_v(const u16* __restrict__ vb,
                                                     u16* __restrict__ vt) {
    __shared__ u16 t[64][72];
    int bh = blockIdx.y, s0 = blockIdx.x * 64;
    int tid = threadIdx.x;
    for (int i = 0; i < 2; ++i) {
        int e = i * 256 + tid;
        int row = e >> 3, ch = (e & 7) * 8;
        uint4 v = *(const uint4*)(vb + ((size_t)bh * 1024 + s0 + row) * 64 + ch);
        *(uint4*)&t[row][ch] = v;
    }
    __syncthreads();
    for (int i = 0; i < 2; ++i) {
        int e = i * 256 + tid;
        int d = e >> 3, ch = (e & 7) * 8;
        union { u16 h[8]; uint4 q; } o;
        for (int j = 0; j < 8; ++j) o.h[j] = t[ch + j][d];
        *(uint4*)(vt + ((size_t)bh * 64 + d) * 1024 + s0 + ch) = o.q;
    }
}

// ---------------- fused masked attention v7b ----------------
// r9-proven v5 sync structure + exp2 (pre-scaled Q) + setprio. bf16 packing
// REVERTED to the r9-proven manual cvt_bf pack (r12's v_cvt_pk_bf16_f32 asm
// produced absmax 0.21 — single-hypothesis revert; do not reintroduce without
// ISA-verified operand order).
__global__ __launch_bounds__(256, 3) void k_attn(const u16* __restrict__ qb,
                                                 const u16* __restrict__ kb,
                                                 const u16* __restrict__ vt,
                                                 const u64* __restrict__ mbits,
                                                 u16* __restrict__ ctx) {
    __shared__ u16 Kd[2][64 * 64];
    __shared__ u16 Vd[2][64 * 64];
    int tid = threadIdx.x, wv = tid >> 6, lane = tid & 63;
    int r = lane & 15, g = lane >> 4;
    int q0 = blockIdx.x * 128, bh = blockIdx.y;
    int b = bh >> 4, h = bh & 15;

    // Q fragments: 2 q-groups of 16 rows (B-operand: lane holds Q[q=r][g*8..])
    bf16x8 aq[2][2];
#pragma unroll
    for (int qg = 0; qg < 2; ++qg) {
        const u16* qp = qb + ((size_t)bh * 1024 + q0 + wv * 32 + qg * 16 + r) * 64 + g * 8;
        aq[qg][0] = *(const bf16x8*)qp;
        aq[qg][1] = *(const bf16x8*)(qp + 32);
    }

    f32x4 of[2][4] = {};
    f32x4 zacc[2] = {};
    const bf16x8 vone = {(__bf16)1.f, (__bf16)1.f, (__bf16)1.f, (__bf16)1.f,
                         (__bf16)1.f, (__bf16)1.f, (__bf16)1.f, (__bf16)1.f};

    // mask row pointer: [b][t][row] layout; lane needs rows wv*32 + qg*16 + r
    const u64* mrow = mbits + ((size_t)b * 16) * 1024 + q0 + wv * 32 + r;
    u64 mbc[2] = {mrow[0], mrow[16]};

    // prologue: stage tile 0 (K rows permuted by kappa; V rows natural)
    for (int i2 = 0; i2 < 2; ++i2) {
        int e = i2 * 256 + tid;
        int s = e >> 3, c = e & 7;
        int cs = (c ^ (s & 7)) * 8;
        int kr = (s & 0x20) | ((s & 0x0C) << 1) | ((s & 0x10) >> 2) | (s & 3);
        gload16(kb + ((size_t)bh * 1024 + kr) * 64 + cs, Kd[0] + (size_t)e * 8);
        gload16(vt + ((size_t)bh * 64 + s) * 1024 + cs, Vd[0] + (size_t)e * 8);
    }
    __syncthreads();

    for (int t = 0; t < 16; ++t) {
        int cur = t & 1;
        u64 mbn0 = 0, mbn1 = 0;
        if (t < 15) {                                 // stage next tile early
            int ktn = (t + 1) * 64;
            for (int i2 = 0; i2 < 2; ++i2) {
                int e = i2 * 256 + tid;
                int s = e >> 3, c = e & 7;
                int cs = (c ^ (s & 7)) * 8;
                int kr = (s & 0x20) | ((s & 0x0C) << 1) | ((s & 0x10) >> 2) | (s & 3);
                gload16(kb + ((size_t)bh * 1024 + ktn + kr) * 64 + cs, Kd[cur ^ 1] + (size_t)e * 8);
                gload16(vt + ((size_t)bh * 64 + s) * 1024 + ktn + cs, Vd[cur ^ 1] + (size_t)e * 8);
            }
            mbn0 = mrow[(size_t)(t + 1) * 1024];
            mbn1 = mrow[(size_t)(t + 1) * 1024 + 16];
        }
        const u16* K = Kd[cur];
        const u16* V = Vd[cur];

        // K A-fragments (shared by both q-groups)
        bf16x8 bk0[4], bk1[4];
#pragma unroll
        for (int nf = 0; nf < 4; ++nf) {
            int rowk = (nf * 16 + r) * 64;
            bk0[nf] = *(const bf16x8*)&K[rowk + ((g ^ (r & 7)) << 3)];
            bk1[nf] = *(const bf16x8*)&K[rowk + (((g + 4) ^ (r & 7)) << 3)];
        }

        bf16x8 pfr[2][2];
#pragma unroll
        for (int qg = 0; qg < 2; ++qg) {
            // S^T: lane (r,g) gets S[q=r][kappa(16nf+4g+i)] (pre-scaled by log2e)
            f32x4 sf[4];
            __builtin_amdgcn_s_setprio(1);
#pragma unroll
            for (int nf = 0; nf < 4; ++nf) {
                f32x4 z = {0.f, 0.f, 0.f, 0.f};
                z = __builtin_amdgcn_mfma_f32_16x16x32_bf16(bk0[nf], aq[qg][0], z, 0, 0, 0);
                sf[nf] = __builtin_amdgcn_mfma_f32_16x16x32_bf16(bk1[nf], aq[qg][1], z, 0, 0, 0);
            }
            __builtin_amdgcn_s_setprio(0);
            // masked exp2 -> packed bf16 pairs == PV B-fragments (manual RNE pack)
            u64 m64 = mbc[qg] >> (g * 8);
            u32 mlo = (u32)m64, mhi = (u32)(m64 >> 32);
            u32 pw[8];
#pragma unroll
            for (int nf = 0; nf < 4; ++nf) {
                u32 nib = ((nf & 2) ? mhi : mlo) >> ((nf & 1) * 4);
                u32 pm0 = ((nib & 1) ? 0xFFFFu : 0u) | ((nib & 2) ? 0xFFFF0000u : 0u);
                u32 pm1 = ((nib & 4) ? 0xFFFFu : 0u) | ((nib & 8) ? 0xFFFF0000u : 0u);
                float e0 = exp2_fast(sf[nf][0]), e1 = exp2_fast(sf[nf][1]);
                float e2 = exp2_fast(sf[nf][2]), e3 = exp2_fast(sf[nf][3]);
                pw[2 * nf]     = (((u32)cvt_bf(e0)) | ((u32)cvt_bf(e1) << 16)) & pm0;
                pw[2 * nf + 1] = (((u32)cvt_bf(e2)) | ((u32)cvt_bf(e3) << 16)) & pm1;
            }
            union { u32 w[4]; bf16x8 v; } f0, f1;
            f0.w[0] = pw[0]; f0.w[1] = pw[1]; f0.w[2] = pw[2]; f0.w[3] = pw[3];
            f1.w[0] = pw[4]; f1.w[1] = pw[5]; f1.w[2] = pw[6]; f1.w[3] = pw[7];
            pfr[qg][0] = f0.v;
            pfr[qg][1] = f1.v;
            // Zm = row-sum via ones-MFMA (all output rows identical)
            __builtin_amdgcn_s_setprio(1);
            zacc[qg] = __builtin_amdgcn_mfma_f32_16x16x32_bf16(vone, pfr[qg][0], zacc[qg], 0, 0, 0);
            zacc[qg] = __builtin_amdgcn_mfma_f32_16x16x32_bf16(vone, pfr[qg][1], zacc[qg], 0, 0, 0);
            __builtin_amdgcn_s_setprio(0);
        }
        // PV: A = V (d-rows), B = P-frags; out = ctx^T fragments
        __builtin_amdgcn_s_setprio(1);
#pragma unroll
        for (int ks = 0; ks < 2; ++ks) {
#pragma unroll
            for (int nf = 0; nf < 4; ++nf) {
                bf16x8 av = *(const bf16x8*)&V[(nf * 16 + r) * 64 + (((ks * 4 + g) ^ (r & 7)) << 3)];
                of[0][nf] = __builtin_amdgcn_mfma_f32_16x16x32_bf16(av, pfr[0][ks], of[0][nf], 0, 0, 0);
                of[1][nf] = __builtin_amdgcn_mfma_f32_16x16x32_bf16(av, pfr[1][ks], of[1][nf], 0, 0, 0);
            }
        }
        __builtin_amdgcn_s_setprio(0);
        mbc[0] = mbn0;
        mbc[1] = mbn1;
        __syncthreads();   // drains vmcnt: stage t+1 + mask prefetch landed
    }

    // epilogue: lane (r,g) owns q-row r of group qg; d = 16nf + 4g + i
#pragma unroll
    for (int qg = 0; qg < 2; ++qg) {
        float inv = 1.0f / zacc[qg][0];
        int qrow = q0 + wv * 32 + qg * 16 + r;
        u16* crow = ctx + ((size_t)(b * 1024 + qrow)) * 1024 + h * 64;
#pragma unroll
        for (int nf = 0; nf < 4; ++nf) {
            u32 w0 = ((u32)cvt_bf(of[qg][nf][0] * inv)) | ((u32)cvt_bf(of[qg][nf][1] * inv) << 16);
            u32 w1 = ((u32)cvt_bf(of[qg][nf][2] * inv)) | ((u32)cvt_bf(of[qg][nf][3] * inv) << 16);
            *(u32*)(crow + nf * 16 + g * 4) = w0;
            *(u32*)(crow + nf * 16 + g * 4 + 2) = w1;
        }
    }
}

extern "C" void kernel_launch(void* const* d_in, const int* in_sizes, int n_in,
                              void* d_out, int out_size, void* d_ws, size_t ws_size,
                              hipStream_t stream) {
    const float* Q_in = (const float*)d_in[0];
    const int*   mask = (const int*)d_in[1];
    const float* Wq = (const float*)d_in[2];
    const float* bq = (const float*)d_in[3];
    const float* Wk = (const float*)d_in[4];
    const float* bk = (const float*)d_in[5];
    const float* Wv = (const float*)d_in[6];
    const float* bv = (const float*)d_in[7];
    const float* Wo = (const float*)d_in[8];
    const float* bo = (const float*)d_in[9];

    char* ws = (char*)d_ws;
    u16* Xb = (u16*)(ws);                      // 16.78 MB  [8192][1024] bf16
    u16* Wt = (u16*)(ws + 16777216);           //  8.39 MB  [4][1024 n][1024 k] bf16
    u16* Qb = (u16*)(ws + 25165824);           // 16.78 MB  [B,H,S,dk] bf16 (x QSCALE)
    u16* Kb = (u16*)(ws + 41943040);           // 16.78 MB  [B,H,S,dk]
    u16* Vb = (u16*)(ws + 58720256);           // 16.78 MB  [B,H,S,dk]
    u16* Vt = (u16*)(ws + 75497472);           // 16.78 MB  [B,H,dk,S]
    u64* Mb = (u64*)(ws + 92274688);           //  1.05 MB  [8][16 t][1024 row] u64
    u16* Ctx = Vb;                             // reuse Vb after transpose

    k_prep<<<10240, 256, 0, stream>>>(Q_in, Xb, Wq, Wk, Wv, Wo, Wt, mask, Mb);
    k_gemm<0><<<dim3(64, 24), 256, 0, stream>>>(Xb, Wt, bq, bk, bv, Qb, Kb, Vb, nullptr);
    k_transpose_v<<<dim3(16, 128), 256, 0, stream>>>(Vb, Vt);
    k_attn<<<dim3(8, 128), 256, 0, stream>>>(Qb, Kb, Vt, Mb, Ctx);
    k_gemm<1><<<dim3(64, 8), 256, 0, stream>>>(Ctx, Wt + (size_t)3 * 1024 * 1024,
                                               bo, nullptr, nullptr,
                                               nullptr, nullptr, nullptr, (float*)d_out);
}